// Round 12
// baseline (228.504 us; speedup 1.0000x reference)
//
#include <hip/hip_runtime.h>
#include <stdint.h>

// Connected-components post-processor, MI355X (gfx950).
// B=8, C=4, H=W=768. argmax -> 3 disjoint class masks per batch, 4-connected
// CCL per mask, keep largest component (tie -> smallest min-raster seed),
// bg = 1 - sum(fg).
//
// Packed parent per batch: parent[b][pix] = (class<<20)|label (bg = -1).
// R10 cooperative single-kernel FAILED (absmax 1.0: exact-capacity coop launch
// and/or insufficient cross-XCD fence for plain loads) -> reverted to the
// benched-good multi-kernel pipeline (R8: 221us, absmax 0), now 4 kernels:
//   k_init          argmax -> classes; run-scan horizontal labels; dedup'd
//                   vertical LDS unions; packed parent written once
//   k_bridge        cross-slab vertical edges, same-class only
//   k_flatten_count 8px/thread: path-compress + wave-run-length count atomics;
//                   per-class (partial,~root) block max -> plain store to ws
//                   (R3: hot atomicMax = 536us cross-XCD ping-pong)
//   k_final         per-block reduce of blockmax (3x288, L2-hot) -> broot;
//                   write 4 channels, 8px/thread   [was separate k_reduce_best]

constexpr int BB    = 8;
constexpr int CC    = 4;
constexpr int HH    = 768;
constexpr int WW    = 768;
constexpr int HWP   = HH * WW;          // 589824 < 2^20
constexpr int TPB   = 256;
constexpr int NBLK8 = HWP / (8 * TPB);  // 288 blocks/batch (8 px/thread)

constexpr int SLAB_ROWS = 4;
constexpr int SLAB_PIX  = SLAB_ROWS * WW;          // 3072
constexpr int NSLAB     = HH / SLAB_ROWS;          // 192
constexpr int GR_SLAB   = SLAB_PIX / 4;            // 768 int4-groups per slab
constexpr int NBOUND    = (NSLAB - 1) * WW;        // 146688 edges per batch
constexpr int NBLK_BR   = (NBOUND + TPB - 1) / TPB;// 573 (exact)

constexpr int CSH  = 20;                 // global packed: class<<20 | pix
constexpr int LMSK = (1 << CSH) - 1;
constexpr int LSH  = 12;                 // local packed: class<<12 | lpix (<3072)
constexpr int LLMSK = (1 << LSH) - 1;

__device__ __forceinline__ int findroot(const int* __restrict__ P, int x) {
  int l = P[x] & LMSK;
  while (l != x) { x = l; l = P[x] & LMSK; }   // labels only decrease: terminates
  return x;
}

// Same-class link-to-min union-find with retry (global, packed values).
__device__ __forceinline__ void unite(int* P, int a, int b, int cls) {
  a = findroot(P, a);
  b = findroot(P, b);
  while (a != b) {
    if (a < b) { int t = a; a = b; b = t; }     // a > b: link a under b
    int old = atomicMin(&P[a], (cls << CSH) | b);
    if ((old & LMSK) == a) return;              // a was root: linked
    a = findroot(P, old & LMSK);
    b = findroot(P, b);
  }
}

// 1) argmax -> classes; zero count scratch; run-start horizontal labels via
//    wave scan; cross-segment stitch + dedup'd vertical unions in LDS; packed
//    parent written once with slab-rooted labels.
__global__ void __launch_bounds__(TPB)
k_init(const float* __restrict__ pred, int* __restrict__ parent,
       float* __restrict__ out) {
  __shared__ int lp[SLAB_PIX];              // 12 KB packed local union-find
  int s = blockIdx.x;                       // slab (rows [4s, 4s+4))
  int b = blockIdx.y;
  int t = threadIdx.x;
  int lane = t & 63;
  const float4* base = (const float4*)(pred + (size_t)b * CC * HWP);
  int4* cntz = (int4*)(out + (size_t)(b * CC + 1) * HWP);   // count scratch
  int4 z4 = make_int4(0, 0, 0, 0);

  unsigned char am[3][4];                   // argmax class (0..3) per pixel
#pragma unroll
  for (int i = 0; i < 3; ++i) {             // 768 groups, 256 threads
    int g = s * GR_SLAB + i * TPB + t;
    float4 v0 = base[g];
    float4 v1 = base[(size_t)(HWP / 4) + g];
    float4 v2 = base[(size_t)(HWP / 4) * 2 + g];
    float4 v3 = base[(size_t)(HWP / 4) * 3 + g];
    float c0[4] = {v0.x, v0.y, v0.z, v0.w};
    float c1[4] = {v1.x, v1.y, v1.z, v1.w};
    float c2[4] = {v2.x, v2.y, v2.z, v2.w};
    float c3[4] = {v3.x, v3.y, v3.z, v3.w};
#pragma unroll
    for (int j = 0; j < 4; ++j) {
      float bv = c0[j]; int a = 0;          // strict > keeps FIRST max (jnp.argmax)
      if (c1[j] > bv) { bv = c1[j]; a = 1; }
      if (c2[j] > bv) { bv = c2[j]; a = 2; }
      if (c3[j] > bv) { bv = c3[j]; a = 3; }
      am[i][j] = (unsigned char)a;
    }
    cntz[g] = z4;                           // zero counts for this batch

    // --- run-start scan within the 256-px wave segment ---
    int cls0 = am[i][0], cls1 = am[i][1], cls2 = am[i][2], cls3 = am[i][3];
    int c4pk = cls0 | (cls1 << 2) | (cls2 << 4) | (cls3 << 6);
    int prevl = __shfl_up(c4pk, 1) >> 6;    // prev lane's last class (lane>0)
    bool b0 = (lane == 0) || (cls0 != (prevl & 3));
    bool b1 = cls1 != cls0;
    bool b2 = cls2 != cls1;
    bool b3 = cls3 != cls2;
    int lb = b3 ? 3 : (b2 ? 2 : (b1 ? 1 : (b0 ? 0 : -1)));   // last boundary in lane
    int v = (lb >= 0) ? lane * 4 + lb : -1;
#pragma unroll
    for (int off = 1; off < 64; off <<= 1) {                 // inclusive max scan
      int o = __shfl_up(v, off);
      if (lane >= off && o > v) v = o;
    }
    int ex = __shfl_up(v, 1);               // exclusive (lane 0: unused, b0 true)
    int rs0 = b0 ? lane * 4     : ex;
    int rs1 = b1 ? lane * 4 + 1 : rs0;
    int rs2 = b2 ? lane * 4 + 2 : rs1;
    int rs3 = b3 ? lane * 4 + 3 : rs2;
    int seg = i * 1024 + (t >> 6) * 256;    // segment base (slab-local px)
    int l0  = seg + lane * 4;
    int4 iv;
    iv.x = cls0 ? (cls0 << LSH) | (seg + rs0) : -1;
    iv.y = cls1 ? (cls1 << LSH) | (seg + rs1) : -1;
    iv.z = cls2 ? (cls2 << LSH) | (seg + rs2) : -1;
    iv.w = cls3 ? (cls3 << LSH) | (seg + rs3) : -1;
    *(int4*)&lp[l0] = iv;
  }

  auto lfind = [&](int x) {
    int l = lp[x] & LLMSK;
    while (l != x) { x = l; l = lp[x] & LLMSK; }
    return x;
  };
  auto lunite = [&](int a, int c, int cls) {
    a = lfind(a); c = lfind(c);
    while (a != c) {
      if (a < c) { int tmp = a; a = c; c = tmp; }
      int old = atomicMin(&lp[a], (cls << LSH) | c);
      if ((old & LLMSK) == a) return;
      a = lfind(old & LLMSK);
      c = lfind(c);
    }
  };

  __syncthreads();

  // stitch horizontal runs across segment boundaries (lane 0, col != 0)
  if (lane == 0) {
#pragma unroll
    for (int i = 0; i < 3; ++i) {
      int seg = i * 1024 + (t >> 6) * 256;
      int cls = am[i][0];
      if (cls && (seg % WW) != 0) {
        int nv = lp[seg - 1];
        if (nv >= 0 && (nv >> LSH) == cls) lunite(seg, seg - 1, cls);
      }
    }
  }
  // vertical edges, dedup'd to one union per overlapping same-class run pair:
  // skip when the left column has the same class pair (that thread unions).
#pragma unroll
  for (int i = 0; i < 3; ++i) {
    int l0   = (i * TPB + t) * 4;
    int row  = l0 / WW;                     // 0..3 (groups never straddle rows)
    int col0 = l0 - row * WW;
    if (row == SLAB_ROWS - 1) continue;
#pragma unroll
    for (int j = 0; j < 4; ++j) {
      int cls = am[i][j];
      if (!cls) continue;
      int l = l0 + j;
      int nv = lp[l + WW];
      if (nv < 0 || (nv >> LSH) != cls) continue;
      if (col0 + j > 0) {
        int lv = lp[l - 1];
        if (lv >= 0 && (lv >> LSH) == cls) {
          int bv = lp[l + WW - 1];
          if (bv >= 0 && (bv >> LSH) == cls) continue;   // left pair unions
        }
      }
      lunite(l, l + WW, cls);
    }
  }
  __syncthreads();
  // flatten + write packed global parent (slab-rooted), coalesced int4
  int gbase = s * SLAB_PIX;
  int* Pb = parent + (size_t)b * HWP;
#pragma unroll
  for (int i = 0; i < 3; ++i) {
    int l0 = (i * TPB + t) * 4;
    int4 pv;
    pv.x = (lp[l0]     >= 0) ? ((lp[l0]     >> LSH) << CSH) | (gbase + lfind(l0))     : -1;
    pv.y = (lp[l0 + 1] >= 0) ? ((lp[l0 + 1] >> LSH) << CSH) | (gbase + lfind(l0 + 1)) : -1;
    pv.z = (lp[l0 + 2] >= 0) ? ((lp[l0 + 2] >> LSH) << CSH) | (gbase + lfind(l0 + 2)) : -1;
    pv.w = (lp[l0 + 3] >= 0) ? ((lp[l0 + 3] >> LSH) << CSH) | (gbase + lfind(l0 + 3)) : -1;
    ((int4*)Pb)[s * GR_SLAB + i * TPB + t] = pv;
  }
}

// 2) cross-slab vertical edges: rows (4k+3, 4k+4), same class only.
__global__ void __launch_bounds__(TPB)
k_bridge(int* __restrict__ parent) {
  int bp = blockIdx.x * TPB + threadIdx.x;
  if (bp >= NBOUND) return;
  int* P = parent + (size_t)blockIdx.y * HWP;
  int k = bp / WW;
  int x = bp - k * WW;
  int p = (SLAB_ROWS * k + SLAB_ROWS - 1) * WW + x;
  int pv = P[p], qv = P[p + WW];
  if (pv >= 0 && qv >= 0 && ((pv ^ qv) >> CSH) == 0)
    unite(P, p, p + WW, pv >> CSH);
}

// 3) flatten + count, 8 px/thread (R11: ILP on the root chases, 8x fewer
//    blockmax entries).  Wave-aggregated size atomics per 256-px segment;
//    atomicAdd's return gives the running partial -> pack(partial, ~root);
//    per-class block max plain-stored to blockmax (in d_ws).
__global__ void __launch_bounds__(TPB)
k_flatten_count(int* __restrict__ parent, float* __restrict__ out,
                unsigned long long* __restrict__ blockmax) {
  int b   = blockIdx.y;
  int* P  = parent + (size_t)b * HWP;
  uint32_t* cnt = (uint32_t*)(out + (size_t)(b * CC + 1) * HWP);
  int lane = threadIdx.x & 63;
  unsigned long long pc0 = 0ull, pc1 = 0ull, pc2 = 0ull;
#pragma unroll
  for (int k2 = 0; k2 < 8; ++k2) {
    int pix = blockIdx.x * (8 * TPB) + k2 * TPB + threadIdx.x;
    int pv  = P[pix];
    int r = -1, cls = 0;
    if (pv >= 0) {
      cls = pv >> CSH;
      int lbl = pv & LMSK;
      r = (lbl == pix) ? pix : findroot(P, lbl);
      if (r != lbl) P[pix] = (cls << CSH) | r;
    }
    int prev = __shfl_up(r, 1);
    bool bound = (lane == 0) || (prev != r);
    unsigned long long lb = __ballot(bound);
    if (bound && r >= 0) {
      unsigned long long rest = (lane == 63) ? 0ull : (lb >> (lane + 1));
      int nxt = rest ? (lane + 1 + (int)__builtin_ctzll(rest)) : 64;
      int len = nxt - lane;
      uint32_t old = atomicAdd(cnt + r, (uint32_t)len);
      unsigned long long pack =
          (((unsigned long long)(old + (uint32_t)len)) << 32) |
          (unsigned long long)(0xFFFFFFFFu - (uint32_t)r);
      if (cls == 1 && pack > pc0) pc0 = pack;
      if (cls == 2 && pack > pc1) pc1 = pack;
      if (cls == 3 && pack > pc2) pc2 = pack;
    }
  }
  __shared__ unsigned long long sm[3][TPB / 64];
  int wid = threadIdx.x >> 6;
  unsigned long long pcs[3] = {pc0, pc1, pc2};
#pragma unroll
  for (int cm = 0; cm < 3; ++cm) {
    unsigned long long v = pcs[cm];
#pragma unroll
    for (int off = 32; off > 0; off >>= 1) {
      unsigned long long o = __shfl_down(v, off);
      if (o > v) v = o;
    }
    if (lane == 0) sm[cm][wid] = v;
  }
  __syncthreads();
  if (threadIdx.x < 3) {
    int cm = threadIdx.x;
    unsigned long long bm = sm[cm][0];
#pragma unroll
    for (int i = 1; i < TPB / 64; ++i) if (sm[cm][i] > bm) bm = sm[cm][i];
    blockmax[(size_t)(b * 3 + cm) * NBLK8 + blockIdx.x] = bm;  // plain store
  }
}

// 4) reduce blockmax (3 x 288, L2-hot) -> broot per batch, then write all 4
//    output channels, 8 px/thread.  [R11: fused former k_reduce_best]
__global__ void __launch_bounds__(TPB)
k_final(const int* __restrict__ parent,
        const unsigned long long* __restrict__ blockmax,
        float* __restrict__ out) {
  int b = blockIdx.y;
  __shared__ int sbroot[3];
  __shared__ unsigned long long red[TPB / 64];
  int lane = threadIdx.x & 63, wid = threadIdx.x >> 6;
#pragma unroll
  for (int cm = 0; cm < 3; ++cm) {
    const unsigned long long* bm = blockmax + (size_t)(b * 3 + cm) * NBLK8;
    unsigned long long v = 0ull;
    for (int i = threadIdx.x; i < NBLK8; i += TPB) {
      unsigned long long o = bm[i];
      if (o > v) v = o;
    }
#pragma unroll
    for (int off = 32; off > 0; off >>= 1) {
      unsigned long long o = __shfl_down(v, off);
      if (o > v) v = o;
    }
    if (lane == 0) red[wid] = v;
    __syncthreads();
    if (threadIdx.x == 0) {
      unsigned long long b0 = red[0];
#pragma unroll
      for (int i = 1; i < TPB / 64; ++i) if (red[i] > b0) b0 = red[i];
      sbroot[cm] = (b0 >> 32) ? (int)(0xFFFFFFFFu - (uint32_t)b0) : -2;  // -2: empty
    }
    __syncthreads();                        // red reuse + sbroot visibility
  }
  int broot[3] = {sbroot[0], sbroot[1], sbroot[2]};

  const int4* Pb = (const int4*)(parent + (size_t)b * HWP);
  float4* ob = (float4*)(out + (size_t)b * CC * HWP);
#pragma unroll
  for (int h = 0; h < 2; ++h) {
    int g = blockIdx.x * (2 * TPB) + h * TPB + threadIdx.x;
    int4 pv = Pb[g];
    int pvs[4] = {pv.x, pv.y, pv.z, pv.w};
    float4 ch[4];
    float* chf = (float*)ch;
#pragma unroll
    for (int c = 0; c < 4; ++c) ch[c] = make_float4(0.f, 0.f, 0.f, 0.f);
#pragma unroll
    for (int j = 0; j < 4; ++j) {
      int v = pvs[j];
      if (v >= 0) {
        int cls = v >> CSH;                  // 1..3
        bool match = (v & LMSK) == broot[cls - 1];
        chf[cls * 4 + j] = match ? 1.f : 0.f;
        chf[j]           = match ? 0.f : 1.f;   // bg
      } else {
        chf[j] = 1.f;                        // bg pixel
      }
    }
#pragma unroll
    for (int c = 0; c < 4; ++c)
      ob[(size_t)(HWP / 4) * c + g] = ch[c];
  }
}

extern "C" void kernel_launch(void* const* d_in, const int* in_sizes, int n_in,
                              void* d_out, int out_size, void* d_ws, size_t ws_size,
                              hipStream_t stream) {
  const float* pred = (const float*)d_in[0];
  float* out = (float*)d_out;

  int* parent = (int*)d_ws;   // 8 * 589824 * 4 B = 18.9 MB (packed class|label)
  // blockmax in d_ws (NOT d_out: k_final now reads it while writing output):
  // 24 * 288 * 8 B = 55 KB.
  unsigned long long* blockmax =
      (unsigned long long*)((char*)d_ws + (size_t)BB * HWP * sizeof(int));
  // Count scratch: channel 1 of each batch in d_out (zeroed by k_init),
  // fully overwritten by k_final afterwards.

  dim3 blk(TPB);
  k_init          <<<dim3(NSLAB, BB),   blk, 0, stream>>>(pred, parent, out);
  k_bridge        <<<dim3(NBLK_BR, BB), blk, 0, stream>>>(parent);
  k_flatten_count <<<dim3(NBLK8, BB),   blk, 0, stream>>>(parent, out, blockmax);
  k_final         <<<dim3(NBLK8, BB),   blk, 0, stream>>>(parent, blockmax, out);
}

// Round 13
// 224.241 us; speedup vs baseline: 1.0190x; 1.0190x over previous
//
#include <hip/hip_runtime.h>
#include <stdint.h>

// Connected-components post-processor, MI355X (gfx950).
// B=8, C=4, H=W=768. argmax -> 3 disjoint class masks per batch, 4-connected
// CCL per mask, keep largest component (tie -> smallest min-raster seed),
// bg = 1 - sum(fg).
//
// Packed parent per batch: parent[b][pix] = (class<<20)|label (bg = -1).
// R12 lesson: fusing the best-reduce into k_final made every one of 2304
// blocks pay a ~2-5us serial reduce prologue (k_final 47.5us @ 1.6TB/s) ->
// restored the 24-block k_reduce_best; k_final is pure streaming again.
// Pipeline (5 kernels):
//   k_init          argmax -> classes; run-scan horizontal labels; dedup'd
//                   vertical LDS unions; packed parent written once
//   k_bridge        cross-slab vertical edges, same-class only
//   k_flatten_count 8px/thread: path-compress + wave-run-length count atomics;
//                   per-class (partial,~root) block max -> plain store to ws
//                   (R3: hot atomicMax = 536us cross-XCD ping-pong)
//   k_reduce_best   24 blocks: max-reduce 3x288 block maxima -> best[m]
//   k_final         read best (3 scalars) + write 4 channels, 8px/thread

constexpr int BB    = 8;
constexpr int CC    = 4;
constexpr int HH    = 768;
constexpr int WW    = 768;
constexpr int HWP   = HH * WW;          // 589824 < 2^20
constexpr int NMASK = BB * (CC - 1);    // 24
constexpr int TPB   = 256;
constexpr int NBLK8 = HWP / (8 * TPB);  // 288 blocks/batch (8 px/thread)

constexpr int SLAB_ROWS = 4;
constexpr int SLAB_PIX  = SLAB_ROWS * WW;          // 3072
constexpr int NSLAB     = HH / SLAB_ROWS;          // 192
constexpr int GR_SLAB   = SLAB_PIX / 4;            // 768 int4-groups per slab
constexpr int NBOUND    = (NSLAB - 1) * WW;        // 146688 edges per batch
constexpr int NBLK_BR   = (NBOUND + TPB - 1) / TPB;// 573 (exact)

constexpr int CSH  = 20;                 // global packed: class<<20 | pix
constexpr int LMSK = (1 << CSH) - 1;
constexpr int LSH  = 12;                 // local packed: class<<12 | lpix (<3072)
constexpr int LLMSK = (1 << LSH) - 1;

__device__ __forceinline__ int findroot(const int* __restrict__ P, int x) {
  int l = P[x] & LMSK;
  while (l != x) { x = l; l = P[x] & LMSK; }   // labels only decrease: terminates
  return x;
}

// Same-class link-to-min union-find with retry (global, packed values).
__device__ __forceinline__ void unite(int* P, int a, int b, int cls) {
  a = findroot(P, a);
  b = findroot(P, b);
  while (a != b) {
    if (a < b) { int t = a; a = b; b = t; }     // a > b: link a under b
    int old = atomicMin(&P[a], (cls << CSH) | b);
    if ((old & LMSK) == a) return;              // a was root: linked
    a = findroot(P, old & LMSK);
    b = findroot(P, b);
  }
}

// 1) argmax -> classes; zero count scratch; run-start horizontal labels via
//    wave scan; cross-segment stitch + dedup'd vertical unions in LDS; packed
//    parent written once with slab-rooted labels.
__global__ void __launch_bounds__(TPB)
k_init(const float* __restrict__ pred, int* __restrict__ parent,
       float* __restrict__ out) {
  __shared__ int lp[SLAB_PIX];              // 12 KB packed local union-find
  int s = blockIdx.x;                       // slab (rows [4s, 4s+4))
  int b = blockIdx.y;
  int t = threadIdx.x;
  int lane = t & 63;
  const float4* base = (const float4*)(pred + (size_t)b * CC * HWP);
  int4* cntz = (int4*)(out + (size_t)(b * CC + 1) * HWP);   // count scratch
  int4 z4 = make_int4(0, 0, 0, 0);

  unsigned char am[3][4];                   // argmax class (0..3) per pixel
#pragma unroll
  for (int i = 0; i < 3; ++i) {             // 768 groups, 256 threads
    int g = s * GR_SLAB + i * TPB + t;
    float4 v0 = base[g];
    float4 v1 = base[(size_t)(HWP / 4) + g];
    float4 v2 = base[(size_t)(HWP / 4) * 2 + g];
    float4 v3 = base[(size_t)(HWP / 4) * 3 + g];
    float c0[4] = {v0.x, v0.y, v0.z, v0.w};
    float c1[4] = {v1.x, v1.y, v1.z, v1.w};
    float c2[4] = {v2.x, v2.y, v2.z, v2.w};
    float c3[4] = {v3.x, v3.y, v3.z, v3.w};
#pragma unroll
    for (int j = 0; j < 4; ++j) {
      float bv = c0[j]; int a = 0;          // strict > keeps FIRST max (jnp.argmax)
      if (c1[j] > bv) { bv = c1[j]; a = 1; }
      if (c2[j] > bv) { bv = c2[j]; a = 2; }
      if (c3[j] > bv) { bv = c3[j]; a = 3; }
      am[i][j] = (unsigned char)a;
    }
    cntz[g] = z4;                           // zero counts for this batch

    // --- run-start scan within the 256-px wave segment ---
    int cls0 = am[i][0], cls1 = am[i][1], cls2 = am[i][2], cls3 = am[i][3];
    int c4pk = cls0 | (cls1 << 2) | (cls2 << 4) | (cls3 << 6);
    int prevl = __shfl_up(c4pk, 1) >> 6;    // prev lane's last class (lane>0)
    bool b0 = (lane == 0) || (cls0 != (prevl & 3));
    bool b1 = cls1 != cls0;
    bool b2 = cls2 != cls1;
    bool b3 = cls3 != cls2;
    int lb = b3 ? 3 : (b2 ? 2 : (b1 ? 1 : (b0 ? 0 : -1)));   // last boundary in lane
    int v = (lb >= 0) ? lane * 4 + lb : -1;
#pragma unroll
    for (int off = 1; off < 64; off <<= 1) {                 // inclusive max scan
      int o = __shfl_up(v, off);
      if (lane >= off && o > v) v = o;
    }
    int ex = __shfl_up(v, 1);               // exclusive (lane 0: unused, b0 true)
    int rs0 = b0 ? lane * 4     : ex;
    int rs1 = b1 ? lane * 4 + 1 : rs0;
    int rs2 = b2 ? lane * 4 + 2 : rs1;
    int rs3 = b3 ? lane * 4 + 3 : rs2;
    int seg = i * 1024 + (t >> 6) * 256;    // segment base (slab-local px)
    int l0  = seg + lane * 4;
    int4 iv;
    iv.x = cls0 ? (cls0 << LSH) | (seg + rs0) : -1;
    iv.y = cls1 ? (cls1 << LSH) | (seg + rs1) : -1;
    iv.z = cls2 ? (cls2 << LSH) | (seg + rs2) : -1;
    iv.w = cls3 ? (cls3 << LSH) | (seg + rs3) : -1;
    *(int4*)&lp[l0] = iv;
  }

  auto lfind = [&](int x) {
    int l = lp[x] & LLMSK;
    while (l != x) { x = l; l = lp[x] & LLMSK; }
    return x;
  };
  auto lunite = [&](int a, int c, int cls) {
    a = lfind(a); c = lfind(c);
    while (a != c) {
      if (a < c) { int tmp = a; a = c; c = tmp; }
      int old = atomicMin(&lp[a], (cls << LSH) | c);
      if ((old & LLMSK) == a) return;
      a = lfind(old & LLMSK);
      c = lfind(c);
    }
  };

  __syncthreads();

  // stitch horizontal runs across segment boundaries (lane 0, col != 0)
  if (lane == 0) {
#pragma unroll
    for (int i = 0; i < 3; ++i) {
      int seg = i * 1024 + (t >> 6) * 256;
      int cls = am[i][0];
      if (cls && (seg % WW) != 0) {
        int nv = lp[seg - 1];
        if (nv >= 0 && (nv >> LSH) == cls) lunite(seg, seg - 1, cls);
      }
    }
  }
  // vertical edges, dedup'd to one union per overlapping same-class run pair:
  // skip when the left column has the same class pair (that thread unions).
#pragma unroll
  for (int i = 0; i < 3; ++i) {
    int l0   = (i * TPB + t) * 4;
    int row  = l0 / WW;                     // 0..3 (groups never straddle rows)
    int col0 = l0 - row * WW;
    if (row == SLAB_ROWS - 1) continue;
#pragma unroll
    for (int j = 0; j < 4; ++j) {
      int cls = am[i][j];
      if (!cls) continue;
      int l = l0 + j;
      int nv = lp[l + WW];
      if (nv < 0 || (nv >> LSH) != cls) continue;
      if (col0 + j > 0) {
        int lv = lp[l - 1];
        if (lv >= 0 && (lv >> LSH) == cls) {
          int bv = lp[l + WW - 1];
          if (bv >= 0 && (bv >> LSH) == cls) continue;   // left pair unions
        }
      }
      lunite(l, l + WW, cls);
    }
  }
  __syncthreads();
  // flatten + write packed global parent (slab-rooted), coalesced int4
  int gbase = s * SLAB_PIX;
  int* Pb = parent + (size_t)b * HWP;
#pragma unroll
  for (int i = 0; i < 3; ++i) {
    int l0 = (i * TPB + t) * 4;
    int4 pv;
    pv.x = (lp[l0]     >= 0) ? ((lp[l0]     >> LSH) << CSH) | (gbase + lfind(l0))     : -1;
    pv.y = (lp[l0 + 1] >= 0) ? ((lp[l0 + 1] >> LSH) << CSH) | (gbase + lfind(l0 + 1)) : -1;
    pv.z = (lp[l0 + 2] >= 0) ? ((lp[l0 + 2] >> LSH) << CSH) | (gbase + lfind(l0 + 2)) : -1;
    pv.w = (lp[l0 + 3] >= 0) ? ((lp[l0 + 3] >> LSH) << CSH) | (gbase + lfind(l0 + 3)) : -1;
    ((int4*)Pb)[s * GR_SLAB + i * TPB + t] = pv;
  }
}

// 2) cross-slab vertical edges: rows (4k+3, 4k+4), same class only.
__global__ void __launch_bounds__(TPB)
k_bridge(int* __restrict__ parent) {
  int bp = blockIdx.x * TPB + threadIdx.x;
  if (bp >= NBOUND) return;
  int* P = parent + (size_t)blockIdx.y * HWP;
  int k = bp / WW;
  int x = bp - k * WW;
  int p = (SLAB_ROWS * k + SLAB_ROWS - 1) * WW + x;
  int pv = P[p], qv = P[p + WW];
  if (pv >= 0 && qv >= 0 && ((pv ^ qv) >> CSH) == 0)
    unite(P, p, p + WW, pv >> CSH);
}

// 3) flatten + count, 8 px/thread.  Wave-aggregated size atomics per 256-px
//    segment; atomicAdd's return gives the running partial ->
//    pack(partial, ~root); per-class block max plain-stored to blockmax.
__global__ void __launch_bounds__(TPB)
k_flatten_count(int* __restrict__ parent, float* __restrict__ out,
                unsigned long long* __restrict__ blockmax) {
  int b   = blockIdx.y;
  int* P  = parent + (size_t)b * HWP;
  uint32_t* cnt = (uint32_t*)(out + (size_t)(b * CC + 1) * HWP);
  int lane = threadIdx.x & 63;
  unsigned long long pc0 = 0ull, pc1 = 0ull, pc2 = 0ull;
#pragma unroll
  for (int k2 = 0; k2 < 8; ++k2) {
    int pix = blockIdx.x * (8 * TPB) + k2 * TPB + threadIdx.x;
    int pv  = P[pix];
    int r = -1, cls = 0;
    if (pv >= 0) {
      cls = pv >> CSH;
      int lbl = pv & LMSK;
      r = (lbl == pix) ? pix : findroot(P, lbl);
      if (r != lbl) P[pix] = (cls << CSH) | r;
    }
    int prev = __shfl_up(r, 1);
    bool bound = (lane == 0) || (prev != r);
    unsigned long long lb = __ballot(bound);
    if (bound && r >= 0) {
      unsigned long long rest = (lane == 63) ? 0ull : (lb >> (lane + 1));
      int nxt = rest ? (lane + 1 + (int)__builtin_ctzll(rest)) : 64;
      int len = nxt - lane;
      uint32_t old = atomicAdd(cnt + r, (uint32_t)len);
      unsigned long long pack =
          (((unsigned long long)(old + (uint32_t)len)) << 32) |
          (unsigned long long)(0xFFFFFFFFu - (uint32_t)r);
      if (cls == 1 && pack > pc0) pc0 = pack;
      if (cls == 2 && pack > pc1) pc1 = pack;
      if (cls == 3 && pack > pc2) pc2 = pack;
    }
  }
  __shared__ unsigned long long sm[3][TPB / 64];
  int wid = threadIdx.x >> 6;
  unsigned long long pcs[3] = {pc0, pc1, pc2};
#pragma unroll
  for (int cm = 0; cm < 3; ++cm) {
    unsigned long long v = pcs[cm];
#pragma unroll
    for (int off = 32; off > 0; off >>= 1) {
      unsigned long long o = __shfl_down(v, off);
      if (o > v) v = o;
    }
    if (lane == 0) sm[cm][wid] = v;
  }
  __syncthreads();
  if (threadIdx.x < 3) {
    int cm = threadIdx.x;
    unsigned long long bm = sm[cm][0];
#pragma unroll
    for (int i = 1; i < TPB / 64; ++i) if (sm[cm][i] > bm) bm = sm[cm][i];
    blockmax[(size_t)(b * 3 + cm) * NBLK8 + blockIdx.x] = bm;  // plain store
  }
}

// 4) reduce 288 block maxima per (batch,class) -> best[m].  24 blocks.
__global__ void __launch_bounds__(TPB)
k_reduce_best(const unsigned long long* __restrict__ blockmax,
              unsigned long long* __restrict__ best) {
  int m = blockIdx.x;
  const unsigned long long* bm = blockmax + (size_t)m * NBLK8;
  unsigned long long v = (threadIdx.x < NBLK8) ? bm[threadIdx.x] : 0ull;
  {
    int i = threadIdx.x + TPB;
    if (i < NBLK8) { unsigned long long o = bm[i]; if (o > v) v = o; }
  }
#pragma unroll
  for (int off = 32; off > 0; off >>= 1) {
    unsigned long long o = __shfl_down(v, off);
    if (o > v) v = o;
  }
  __shared__ unsigned long long sm[TPB / 64];
  int lane = threadIdx.x & 63, wid = threadIdx.x >> 6;
  if (lane == 0) sm[wid] = v;
  __syncthreads();
  if (threadIdx.x == 0) {
    unsigned long long b0 = sm[0];
#pragma unroll
    for (int i = 1; i < TPB / 64; ++i) if (sm[i] > b0) b0 = sm[i];
    best[m] = b0;                       // 0 when mask empty
  }
}

// 5) write all 4 output channels, 8 px/thread (pure streaming; best read as
//    3 scalar loads -- no per-block reduce, R12 lesson).
__global__ void __launch_bounds__(TPB)
k_final(const int* __restrict__ parent,
        const unsigned long long* __restrict__ best,
        float* __restrict__ out) {
  int b = blockIdx.y;
  int broot[3];
#pragma unroll
  for (int cm = 0; cm < 3; ++cm) {
    unsigned long long bv = best[b * 3 + cm];            // uniform -> scalar
    broot[cm] = (bv >> 32) ? (int)(0xFFFFFFFFu - (uint32_t)bv) : -2;  // -2: empty
  }
  const int4* Pb = (const int4*)(parent + (size_t)b * HWP);
  float4* ob = (float4*)(out + (size_t)b * CC * HWP);
#pragma unroll
  for (int h = 0; h < 2; ++h) {
    int g = blockIdx.x * (2 * TPB) + h * TPB + threadIdx.x;
    int4 pv = Pb[g];
    int pvs[4] = {pv.x, pv.y, pv.z, pv.w};
    float4 ch[4];
    float* chf = (float*)ch;
#pragma unroll
    for (int c = 0; c < 4; ++c) ch[c] = make_float4(0.f, 0.f, 0.f, 0.f);
#pragma unroll
    for (int j = 0; j < 4; ++j) {
      int v = pvs[j];
      if (v >= 0) {
        int cls = v >> CSH;                  // 1..3
        bool match = (v & LMSK) == broot[cls - 1];
        chf[cls * 4 + j] = match ? 1.f : 0.f;
        chf[j]           = match ? 0.f : 1.f;   // bg
      } else {
        chf[j] = 1.f;                        // bg pixel
      }
    }
#pragma unroll
    for (int c = 0; c < 4; ++c)
      ob[(size_t)(HWP / 4) * c + g] = ch[c];
  }
}

extern "C" void kernel_launch(void* const* d_in, const int* in_sizes, int n_in,
                              void* d_out, int out_size, void* d_ws, size_t ws_size,
                              hipStream_t stream) {
  const float* pred = (const float*)d_in[0];
  float* out = (float*)d_out;

  int* parent = (int*)d_ws;   // 8 * 589824 * 4 B = 18.9 MB (packed class|label)
  unsigned long long* blockmax =
      (unsigned long long*)((char*)d_ws + (size_t)BB * HWP * sizeof(int));  // 55 KB
  unsigned long long* best = blockmax + (size_t)NMASK * NBLK8;              // 192 B
  // Count scratch: channel 1 of each batch in d_out (zeroed by k_init),
  // fully overwritten by k_final afterwards.

  dim3 blk(TPB);
  k_init          <<<dim3(NSLAB, BB),   blk, 0, stream>>>(pred, parent, out);
  k_bridge        <<<dim3(NBLK_BR, BB), blk, 0, stream>>>(parent);
  k_flatten_count <<<dim3(NBLK8, BB),   blk, 0, stream>>>(parent, out, blockmax);
  k_reduce_best   <<<dim3(NMASK),       blk, 0, stream>>>(blockmax, best);
  k_final         <<<dim3(NBLK8, BB),   blk, 0, stream>>>(parent, best, out);
}